// Round 1
// baseline (279.290 us; speedup 1.0000x reference)
//
#include <hip/hip_runtime.h>
#include <hip/hip_bf16.h>

typedef unsigned short u16;
typedef unsigned int u32;
typedef __attribute__((ext_vector_type(8))) short bh8;   // 8 bf16 in 4 VGPR (MFMA A/B frag)
typedef __attribute__((ext_vector_type(4))) float f4;    // MFMA C/D frag

#define T_   4
#define B_   16
#define C_   512
#define N_   256
#define M2_  4096          // B_*N_ rows per t
#define MT_  16384         // T_*M2_
#define OC3_ 1536          // q,k,v output channels concatenated

// ---------------- helpers ----------------
__device__ __forceinline__ u16 f2bf(float f) {
  u32 u = __float_as_uint(f);
  u32 r = (u + 0x7FFFu + ((u >> 16) & 1u)) >> 16;   // RNE
  return (u16)r;
}
__device__ __forceinline__ void gl_lds16(const void* g, void* l) {
  __builtin_amdgcn_global_load_lds(
      (const __attribute__((address_space(1))) unsigned int*)g,
      (__attribute__((address_space(3))) unsigned int*)l, 16, 0, 0);
}

// ---------------- K0a: weight hi/lo split ----------------
// wcat: (1536, 1024) bf16  [o][0:512]=hi, [o][512:1024]=lo ; wpcat: (512,1024)
__global__ void k_prep_w(const float* __restrict__ wq, const float* __restrict__ wk,
                         const float* __restrict__ wv, const float* __restrict__ wp,
                         u16* __restrict__ wcat, u16* __restrict__ wpcat) {
  int id = blockIdx.x * 256 + threadIdx.x;      // 4*512*512 total
  int mat = id >> 18;
  int rc  = id & 262143;
  int o = rc >> 9, c = rc & 511;
  const float* src = (mat == 0) ? wq : (mat == 1) ? wk : (mat == 2) ? wv : wp;
  float w = src[rc];
  u16 hu = f2bf(w);
  float hf = __uint_as_float(((u32)hu) << 16);
  u16 lu = f2bf(w - hf);
  if (mat < 3) {
    size_t base = ((size_t)(mat * 512 + o)) * 1024 + c;
    wcat[base] = hu; wcat[base + 512] = lu;
  } else {
    size_t base = (size_t)o * 1024 + c;
    wpcat[base] = hu; wpcat[base + 512] = lu;
  }
}

// ---------------- K0b: BN constants ----------------
// bns[ch*4] = {scale, mean, beta, -} for 1536 branch channels
// pss[c*4]  = {bp, pm, scale, beta} for 512 proj channels
__global__ void k_prep_c(const float* qg, const float* qb, const float* qm, const float* qv,
                         const float* kg, const float* kb, const float* km, const float* kv2,
                         const float* vg, const float* vb, const float* vm, const float* vv,
                         const float* pg, const float* pb, const float* pm, const float* pv,
                         const float* bp, float* bns, float* pss) {
  int id = blockIdx.x * 256 + threadIdx.x;
  if (id < 1536) {
    int br = id >> 9, c = id & 511;
    const float *g, *b, *m, *va;
    if (br == 0)      { g = qg; b = qb; m = qm; va = qv; }
    else if (br == 1) { g = kg; b = kb; m = km; va = kv2; }
    else              { g = vg; b = vb; m = vm; va = vv; }
    float s = g[c] / sqrtf(va[c] + 1e-5f);
    bns[id * 4 + 0] = s; bns[id * 4 + 1] = m[c]; bns[id * 4 + 2] = b[c];
  } else if (id < 2048) {
    int c = id - 1536;
    float s = pg[c] / sqrtf(pv[c] + 1e-5f);
    pss[c * 4 + 0] = bp[c]; pss[c * 4 + 1] = pm[c];
    pss[c * 4 + 2] = s;     pss[c * 4 + 3] = pb[c];
  }
}

// ---------------- K1: shortcut LIF + (c,n)->(n,c) transpose, bf16 spikes ----------------
// x: (T,B,C,N) f32 ; xs: (T,B,N,C) bf16 spikes
__global__ void k_lif_x(const float* __restrict__ x, u16* __restrict__ xs) {
  __shared__ u16 sp[4][64][66];
  int b = blockIdx.z, c0 = blockIdx.y * 64, n0 = blockIdx.x * 64;
  int tx = threadIdx.x;
  int nl = tx & 63, cq = tx >> 6;   // cq in 0..3
  float v[16];
#pragma unroll
  for (int i = 0; i < 16; i++) v[i] = 0.f;
  for (int t = 0; t < 4; t++) {
    const float* xb = x + (((size_t)t * B_ + b) * C_ + c0) * N_ + n0;
#pragma unroll
    for (int i = 0; i < 16; i++) {
      int cl = cq * 16 + i;
      float xv = xb[(size_t)cl * N_ + nl];
      v[i] = v[i] + (xv - v[i]) * 0.5f;           // charge, tau=2
      u16 s = 0;
      if (v[i] >= 1.0f) { s = 0x3F80; v[i] = 0.f; } // fire + hard reset
      sp[t][cl][nl] = s;
    }
  }
  __syncthreads();
  for (int t = 0; t < 4; t++) {
    size_t base = (((size_t)t * B_ + b) * N_ + n0) * C_ + c0;
#pragma unroll
    for (int i = 0; i < 16; i++) {
      int cl = tx & 63; int nl2 = (tx >> 6) + i * 4;
      xs[base + (size_t)nl2 * C_ + cl] = sp[t][cl][nl2];
    }
  }
}

// ---------------- K2: fused QKV GEMM + BN + LIF ----------------
// A = xs (t: M2_ x 512 bf16 rows), Wcat (1536 x [hi|lo]), out spq (T*M2_, 1536) bf16 spikes
__launch_bounds__(256, 2)
__global__ void k_qkv_gemm(const u16* __restrict__ xs, const u16* __restrict__ wcat,
                           const float* __restrict__ bns, u16* __restrict__ spq) {
  __shared__ u16 lA[4096];    // 128 x 32
  __shared__ u16 lBh[4096];
  __shared__ u16 lBl[4096];
  int tid = threadIdx.x, lane = tid & 63, wid = tid >> 6;
  int wr = wid >> 1, wc = wid & 1, lr = lane & 15, lq = lane >> 4;
  int m0 = blockIdx.x * 128, o0 = blockIdx.y * 128;

  float scl[4], mn[4], bt[4];
#pragma unroll
  for (int ni = 0; ni < 4; ni++) {
    int ch = o0 + wc * 64 + ni * 16 + lr;
    scl[ni] = bns[ch * 4]; mn[ni] = bns[ch * 4 + 1]; bt[ni] = bns[ch * 4 + 2];
  }
  u32 boff0 = wid * 2048 + lane * 16;
  u32 ms0 = boff0 >> 6, kb0 = boff0 & 63;
  u32 boff1 = boff0 + 1024;
  u32 ms1 = boff1 >> 6, kb1 = boff1 & 63;

  float vst[4][4][4];
#pragma unroll
  for (int a = 0; a < 4; a++)
#pragma unroll
    for (int b = 0; b < 4; b++)
#pragma unroll
      for (int c = 0; c < 4; c++) vst[a][b][c] = 0.f;

  const char* Bb = (const char*)wcat + (size_t)o0 * 2048;

  for (int t = 0; t < 4; t++) {
    f4 acc[4][4];
#pragma unroll
    for (int a = 0; a < 4; a++)
#pragma unroll
      for (int b = 0; b < 4; b++) { acc[a][b][0] = 0.f; acc[a][b][1] = 0.f; acc[a][b][2] = 0.f; acc[a][b][3] = 0.f; }

    const char* Abase = (const char*)xs + ((size_t)t * M2_ + m0) * C_ * 2;
    for (int ks = 0; ks < 16; ks++) {
      int k0 = ks * 32;
      gl_lds16(Abase + (size_t)ms0 * 1024 + k0 * 2 + kb0, (char*)lA + wid * 2048);
      gl_lds16(Abase + (size_t)ms1 * 1024 + k0 * 2 + kb1, (char*)lA + wid * 2048 + 1024);
      gl_lds16(Bb + (size_t)ms0 * 2048 + k0 * 2 + kb0, (char*)lBh + wid * 2048);
      gl_lds16(Bb + (size_t)ms1 * 2048 + k0 * 2 + kb1, (char*)lBh + wid * 2048 + 1024);
      gl_lds16(Bb + 1024 + (size_t)ms0 * 2048 + k0 * 2 + kb0, (char*)lBl + wid * 2048);
      gl_lds16(Bb + 1024 + (size_t)ms1 * 2048 + k0 * 2 + kb1, (char*)lBl + wid * 2048 + 1024);
      __syncthreads();  // compiler drains vmcnt before s_barrier

      bh8 af[4], bhf[4], blf[4];
#pragma unroll
      for (int mi = 0; mi < 4; mi++)
        af[mi] = *(const bh8*)((const char*)lA + ((wr * 64 + mi * 16 + lr) * 32 + lq * 8) * 2);
#pragma unroll
      for (int ni = 0; ni < 4; ni++) {
        bhf[ni] = *(const bh8*)((const char*)lBh + ((wc * 64 + ni * 16 + lr) * 32 + lq * 8) * 2);
        blf[ni] = *(const bh8*)((const char*)lBl + ((wc * 64 + ni * 16 + lr) * 32 + lq * 8) * 2);
      }
#pragma unroll
      for (int mi = 0; mi < 4; mi++)
#pragma unroll
        for (int ni = 0; ni < 4; ni++)
          acc[mi][ni] = __builtin_amdgcn_mfma_f32_16x16x32_bf16(af[mi], bhf[ni], acc[mi][ni], 0, 0, 0);
#pragma unroll
      for (int mi = 0; mi < 4; mi++)
#pragma unroll
        for (int ni = 0; ni < 4; ni++)
          acc[mi][ni] = __builtin_amdgcn_mfma_f32_16x16x32_bf16(af[mi], blf[ni], acc[mi][ni], 0, 0, 0);
      __syncthreads();
    }
    // BN + LIF epilogue (v-state persists across t)
#pragma unroll
    for (int mi = 0; mi < 4; mi++)
#pragma unroll
      for (int ni = 0; ni < 4; ni++)
#pragma unroll
        for (int j = 0; j < 4; j++) {
          float y = acc[mi][ni][j];
          y = (y - mn[ni]) * scl[ni] + bt[ni];
          float vv = vst[mi][ni][j];
          vv = vv + (y - vv) * 0.5f;
          u16 s = 0;
          if (vv >= 1.0f) { s = 0x3F80; vv = 0.f; }
          vst[mi][ni][j] = vv;
          int r = m0 + wr * 64 + mi * 16 + lq * 4 + j;
          int o = o0 + wc * 64 + ni * 16 + lr;
          spq[((size_t)t * M2_ + r) * OC3_ + o] = s;
        }
  }
}

// ---------------- K3a: kv token sum (exact integer counts) ----------------
__global__ void k_kvsum(const u16* __restrict__ spq, float* __restrict__ kvs) {
  int tb = blockIdx.x;            // 0..63  (t*B+b)
  int c = threadIdx.x;            // 512
  const u16* base = spq + (size_t)tb * N_ * OC3_;
  int cnt = 0;
  for (int n = 0; n < N_; n++) {
    u16 kk = base[(size_t)n * OC3_ + 512 + c];
    u16 vv = base[(size_t)n * OC3_ + 1024 + c];
    cnt += (kk & vv) ? 1 : 0;
  }
  kvs[tb * C_ + c] = (float)cnt;
}

// ---------------- K3b: talking-heads LIF (thresh 0.5) -> mask ----------------
__global__ void k_tlif(const float* __restrict__ kvs, unsigned char* __restrict__ mask) {
  int id = blockIdx.x * 256 + threadIdx.x;   // B_*C_
  if (id >= B_ * C_) return;
  int b = id >> 9, c = id & 511;
  float v = 0.f;
  for (int t = 0; t < 4; t++) {
    float xx = kvs[(t * B_ + b) * C_ + c];
    v = v + (xx - v) * 0.5f;
    unsigned char s = 0;
    if (v >= 0.5f) { s = 1; v = 0.f; }
    mask[(t * B_ + b) * C_ + c] = s;
  }
}

// ---------------- K3c: a2 = q_spike AND kv_spike ----------------
__global__ void k_a2(const u16* __restrict__ spq, const unsigned char* __restrict__ mask,
                     u16* __restrict__ a2) {
  size_t id = (size_t)blockIdx.x * 256 + threadIdx.x;   // T*B*N*C
  int c = (int)(id & 511);
  size_t tbn = id >> 9;
  int tb = (int)(tbn >> 8);
  u16 q = spq[tbn * OC3_ + c];
  a2[id] = mask[tb * C_ + c] ? q : (u16)0;
}

// ---------------- K3d: v spikes -> f32 head layout output ----------------
__global__ void k_vout(const u16* __restrict__ spq, float* __restrict__ vout) {
  size_t id = (size_t)blockIdx.x * 256 + threadIdx.x;   // T*B*N*C
  int c = (int)(id & 511);
  size_t tbn = id >> 9;
  int n = (int)(tbn & 255);
  int tb = (int)(tbn >> 8);
  u16 vv = spq[tbn * OC3_ + 1024 + c];
  int h = c >> 6, d = c & 63;
  vout[(((size_t)tb * 8 + h) * 256 + n) * 64 + d] = vv ? 1.0f : 0.0f;
}

// ---------------- K4: projection GEMM (raw f32 out) ----------------
__launch_bounds__(256, 2)
__global__ void k_proj_gemm(const u16* __restrict__ a2, const u16* __restrict__ wpc,
                            float* __restrict__ yp) {
  __shared__ u16 lA[4096];
  __shared__ u16 lBh[4096];
  __shared__ u16 lBl[4096];
  int tid = threadIdx.x, lane = tid & 63, wid = tid >> 6;
  int wr = wid >> 1, wc = wid & 1, lr = lane & 15, lq = lane >> 4;
  int m0 = blockIdx.x * 128, o0 = blockIdx.y * 128;
  u32 boff0 = wid * 2048 + lane * 16;
  u32 ms0 = boff0 >> 6, kb0 = boff0 & 63;
  u32 boff1 = boff0 + 1024;
  u32 ms1 = boff1 >> 6, kb1 = boff1 & 63;
  f4 acc[4][4];
#pragma unroll
  for (int a = 0; a < 4; a++)
#pragma unroll
    for (int b = 0; b < 4; b++) { acc[a][b][0] = 0.f; acc[a][b][1] = 0.f; acc[a][b][2] = 0.f; acc[a][b][3] = 0.f; }

  const char* Abase = (const char*)a2 + (size_t)m0 * 1024;
  const char* Bb = (const char*)wpc + (size_t)o0 * 2048;
  for (int ks = 0; ks < 16; ks++) {
    int k0 = ks * 32;
    gl_lds16(Abase + (size_t)ms0 * 1024 + k0 * 2 + kb0, (char*)lA + wid * 2048);
    gl_lds16(Abase + (size_t)ms1 * 1024 + k0 * 2 + kb1, (char*)lA + wid * 2048 + 1024);
    gl_lds16(Bb + (size_t)ms0 * 2048 + k0 * 2 + kb0, (char*)lBh + wid * 2048);
    gl_lds16(Bb + (size_t)ms1 * 2048 + k0 * 2 + kb1, (char*)lBh + wid * 2048 + 1024);
    gl_lds16(Bb + 1024 + (size_t)ms0 * 2048 + k0 * 2 + kb0, (char*)lBl + wid * 2048);
    gl_lds16(Bb + 1024 + (size_t)ms1 * 2048 + k0 * 2 + kb1, (char*)lBl + wid * 2048 + 1024);
    __syncthreads();
    bh8 af[4], bhf[4], blf[4];
#pragma unroll
    for (int mi = 0; mi < 4; mi++)
      af[mi] = *(const bh8*)((const char*)lA + ((wr * 64 + mi * 16 + lr) * 32 + lq * 8) * 2);
#pragma unroll
    for (int ni = 0; ni < 4; ni++) {
      bhf[ni] = *(const bh8*)((const char*)lBh + ((wc * 64 + ni * 16 + lr) * 32 + lq * 8) * 2);
      blf[ni] = *(const bh8*)((const char*)lBl + ((wc * 64 + ni * 16 + lr) * 32 + lq * 8) * 2);
    }
#pragma unroll
    for (int mi = 0; mi < 4; mi++)
#pragma unroll
      for (int ni = 0; ni < 4; ni++)
        acc[mi][ni] = __builtin_amdgcn_mfma_f32_16x16x32_bf16(af[mi], bhf[ni], acc[mi][ni], 0, 0, 0);
#pragma unroll
    for (int mi = 0; mi < 4; mi++)
#pragma unroll
      for (int ni = 0; ni < 4; ni++)
        acc[mi][ni] = __builtin_amdgcn_mfma_f32_16x16x32_bf16(af[mi], blf[ni], acc[mi][ni], 0, 0, 0);
    __syncthreads();
  }
#pragma unroll
  for (int mi = 0; mi < 4; mi++)
#pragma unroll
    for (int ni = 0; ni < 4; ni++)
#pragma unroll
      for (int j = 0; j < 4; j++) {
        int r = m0 + wr * 64 + mi * 16 + lq * 4 + j;
        int o = o0 + wc * 64 + ni * 16 + lr;
        yp[(size_t)r * C_ + o] = acc[mi][ni][j];
      }
}

// ---------------- K5: (n,o)->(o,n) transpose + bias/BN + identity add ----------------
__global__ void k_final(const float* __restrict__ yp, const float* __restrict__ x,
                        const float* __restrict__ pss, float* __restrict__ out) {
  __shared__ float ty[64][67];
  int tb = blockIdx.z; int o0 = blockIdx.y * 64; int n0 = blockIdx.x * 64;
  int tx = threadIdx.x;
  int ol = tx & 63, nq = tx >> 6;
  int och = o0 + ol;
  float bpv = pss[och * 4], pmv = pss[och * 4 + 1], sv = pss[och * 4 + 2], bbv = pss[och * 4 + 3];
#pragma unroll
  for (int i = 0; i < 16; i++) {
    int nl = nq + i * 4;
    float yv = yp[((size_t)tb * N_ + n0 + nl) * C_ + och];
    float u = yv + bpv;
    u = (u - pmv) * sv + bbv;
    ty[nl][ol] = u;
  }
  __syncthreads();
  int nl2 = tx & 63, oq = tx >> 6;
#pragma unroll
  for (int i = 0; i < 16; i++) {
    int ol2 = oq + i * 4;
    size_t idx = ((size_t)tb * C_ + o0 + ol2) * N_ + n0 + nl2;
    out[idx] = ty[nl2][ol2] + x[idx];
  }
}

// ---------------- launch ----------------
extern "C" void kernel_launch(void* const* d_in, const int* in_sizes, int n_in,
                              void* d_out, int out_size, void* d_ws, size_t ws_size,
                              hipStream_t stream) {
  const float* x  = (const float*)d_in[0];
  const float* wq = (const float*)d_in[1];
  const float* qg = (const float*)d_in[2];
  const float* qb = (const float*)d_in[3];
  const float* qm = (const float*)d_in[4];
  const float* qv = (const float*)d_in[5];
  const float* wk = (const float*)d_in[6];
  const float* kg = (const float*)d_in[7];
  const float* kb = (const float*)d_in[8];
  const float* km = (const float*)d_in[9];
  const float* kv = (const float*)d_in[10];
  const float* wv = (const float*)d_in[11];
  const float* vg = (const float*)d_in[12];
  const float* vb = (const float*)d_in[13];
  const float* vm = (const float*)d_in[14];
  const float* vv = (const float*)d_in[15];
  const float* wp = (const float*)d_in[16];
  const float* bp = (const float*)d_in[17];
  const float* pg = (const float*)d_in[18];
  const float* pb = (const float*)d_in[19];
  const float* pm = (const float*)d_in[20];
  const float* pv = (const float*)d_in[21];

  char* w = (char*)d_ws;
  u16*  XS    = (u16*)(w + 0);                         // 16 MiB  (T,B,N,C) bf16
  u16*  SPQ   = (u16*)(w + 16777216);                  // 48 MiB  (T*M2, 1536) bf16
  u16*  A2    = (u16*)(w + 67108864);                  // 16 MiB  (T*M2, 512) bf16
  float* YP   = (float*)(w + 83886080);                // 32 MiB  (T*M2, 512) f32
  u16*  WCAT  = (u16*)(w + 117440512);                 // 3 MiB
  u16*  WPCAT = (u16*)(w + 120586240);                 // 1 MiB
  float* BNS  = (float*)(w + 121634816);               // 24 KiB
  float* PSS  = (float*)(w + 121659392);               // 8 KiB
  float* KVS  = (float*)(w + 121667584);               // 128 KiB
  unsigned char* MASK = (unsigned char*)(w + 121798656); // 32 KiB

  float* out  = (float*)d_out;                // (T,B,C,N) f32
  float* vout = out + 8388608;                // (T,B,8,N,64) f32

  k_prep_w<<<4096, 256, 0, stream>>>(wq, wk, wv, wp, WCAT, WPCAT);
  k_prep_c<<<8, 256, 0, stream>>>(qg, qb, qm, qv, kg, kb, km, kv,
                                  vg, vb, vm, vv, pg, pb, pm, pv, bp, BNS, PSS);
  k_lif_x<<<dim3(4, 8, 16), 256, 0, stream>>>(x, XS);
  k_qkv_gemm<<<dim3(32, 12), 256, 0, stream>>>(XS, WCAT, BNS, SPQ);
  k_kvsum<<<64, 512, 0, stream>>>(SPQ, KVS);
  k_tlif<<<32, 256, 0, stream>>>(KVS, MASK);
  k_a2<<<32768, 256, 0, stream>>>(SPQ, MASK, A2);
  k_vout<<<32768, 256, 0, stream>>>(SPQ, vout);
  k_proj_gemm<<<dim3(128, 4), 256, 0, stream>>>(A2, WPCAT, YP);
  k_final<<<dim3(4, 8, 64), 256, 0, stream>>>(YP, x, PSS, out);
}

// Round 2
// 216.503 us; speedup vs baseline: 1.2900x; 1.2900x over previous
//
#include <hip/hip_runtime.h>
#include <hip/hip_bf16.h>

typedef unsigned short u16;
typedef unsigned int u32;
typedef __attribute__((ext_vector_type(8))) short bh8;   // 8 bf16 (MFMA A/B frag)
typedef __attribute__((ext_vector_type(4))) short sh4;   // 4 bf16 (8B store)
typedef __attribute__((ext_vector_type(4))) float f4;    // MFMA C/D frag

#define T_   4
#define B_   16
#define C_   512
#define N_   256
#define M2_  4096
#define OC3_ 1536

// ---------------- helpers ----------------
__device__ __forceinline__ u16 f2bf(float f) {
  u32 u = __float_as_uint(f);
  u32 r = (u + 0x7FFFu + ((u >> 16) & 1u)) >> 16;   // RNE
  return (u16)r;
}
__device__ __forceinline__ void gl_lds16(const void* g, void* l) {
  __builtin_amdgcn_global_load_lds(
      (const __attribute__((address_space(1))) unsigned int*)g,
      (__attribute__((address_space(3))) unsigned int*)l, 16, 0, 0);
}

// ---------------- K0a: weight hi/lo split ----------------
__global__ void k_prep_w(const float* __restrict__ wq, const float* __restrict__ wk,
                         const float* __restrict__ wv, const float* __restrict__ wp,
                         u16* __restrict__ wcat, u16* __restrict__ wpcat) {
  int id = blockIdx.x * 256 + threadIdx.x;
  int mat = id >> 18;
  int rc  = id & 262143;
  int o = rc >> 9, c = rc & 511;
  const float* src = (mat == 0) ? wq : (mat == 1) ? wk : (mat == 2) ? wv : wp;
  float w = src[rc];
  u16 hu = f2bf(w);
  float hf = __uint_as_float(((u32)hu) << 16);
  u16 lu = f2bf(w - hf);
  if (mat < 3) {
    size_t base = ((size_t)(mat * 512 + o)) * 1024 + c;
    wcat[base] = hu; wcat[base + 512] = lu;
  } else {
    size_t base = (size_t)o * 1024 + c;
    wpcat[base] = hu; wpcat[base + 512] = lu;
  }
}

// ---------------- K0b: BN constants ----------------
__global__ void k_prep_c(const float* qg, const float* qb, const float* qm, const float* qv,
                         const float* kg, const float* kb, const float* km, const float* kv2,
                         const float* vg, const float* vb, const float* vm, const float* vv,
                         const float* pg, const float* pb, const float* pm, const float* pv,
                         const float* bp, float* bns, float* pss) {
  int id = blockIdx.x * 256 + threadIdx.x;
  if (id < 1536) {
    int br = id >> 9, c = id & 511;
    const float *g, *b, *m, *va;
    if (br == 0)      { g = qg; b = qb; m = qm; va = qv; }
    else if (br == 1) { g = kg; b = kb; m = km; va = kv2; }
    else              { g = vg; b = vb; m = vm; va = vv; }
    float s = g[c] / sqrtf(va[c] + 1e-5f);
    bns[id * 4 + 0] = s; bns[id * 4 + 1] = m[c]; bns[id * 4 + 2] = b[c];
    bns[id * 4 + 3] = 0.f;
  } else if (id < 2048) {
    int c = id - 1536;
    float s = pg[c] / sqrtf(pv[c] + 1e-5f);
    pss[c * 4 + 0] = bp[c]; pss[c * 4 + 1] = pm[c];
    pss[c * 4 + 2] = s;     pss[c * 4 + 3] = pb[c];
  }
}

// ---------------- K1: shortcut LIF + (c,n)->(n,c) transpose, bf16 spikes ----------------
// x: (T,B,C,N) f32 ; xs: (T,B,N,C) bf16 spikes.  float4 loads, u32 transposed stores.
__global__ void k_lif_x(const float* __restrict__ x, u16* __restrict__ xs) {
  __shared__ u16 sp[4][64][68];     // [t][c-local][n-local], pad 68 (8B-aligned rows)
  int b = blockIdx.z, c0 = blockIdx.y * 64, n0 = blockIdx.x * 64;
  int tid = threadIdx.x;
  int rq = tid >> 4;                // c-local row base (0..15)
  int n4 = (tid & 15) * 4;          // n-local start
  float v[16];
#pragma unroll
  for (int i = 0; i < 16; i++) v[i] = 0.f;
  for (int t = 0; t < 4; t++) {
    const float* xb = x + (((size_t)t * 16 + b) * 512 + c0) * 256 + n0;
#pragma unroll
    for (int i = 0; i < 4; i++) {
      int row = rq + i * 16;        // c-local
      f4 xv = *(const f4*)(xb + (size_t)row * 256 + n4);
      sh4 sv;
#pragma unroll
      for (int j = 0; j < 4; j++) {
        float vv = v[i * 4 + j];
        vv = vv + (xv[j] - vv) * 0.5f;
        u16 s = 0;
        if (vv >= 1.0f) { s = 0x3F80; vv = 0.f; }
        v[i * 4 + j] = vv;
        sv[j] = (short)s;
      }
      *(sh4*)&sp[t][row][n4] = sv;
    }
  }
  __syncthreads();
  int cp = (tid & 31) * 2;          // c-local pair
  int nq = tid >> 5;                // n-local base (0..7)
  for (int t = 0; t < 4; t++) {
    u16* ob = xs + (((size_t)t * 16 + b) * 256 + n0) * 512 + c0;
#pragma unroll
    for (int i = 0; i < 8; i++) {
      int n = nq + i * 8;
      u32 w = (u32)sp[t][cp][n] | ((u32)sp[t][cp + 1][n] << 16);
      *(u32*)(ob + (size_t)n * 512 + cp) = w;
    }
  }
}

// ---------------- K2: fused QKV GEMM + BN + LIF ----------------
// 128x96 tile, BK=64, grid 32x16 = 512 blocks (2/CU exact). XOR chunk swizzle.
__launch_bounds__(256, 2)
__global__ void k_qkv_gemm(const u16* __restrict__ xs, const u16* __restrict__ wcat,
                           const float* __restrict__ bns, u16* __restrict__ spq) {
  __shared__ u16 lA[128 * 64];      // 16 KB
  __shared__ u16 lBh[96 * 64];      // 12 KB
  __shared__ u16 lBl[96 * 64];      // 12 KB
  int tid = threadIdx.x, lane = tid & 63, wid = tid >> 6;
  int wr = wid >> 1, wc = wid & 1, lr = lane & 15, lq = lane >> 4;
  int m0 = blockIdx.x * 128, o0 = blockIdx.y * 96;

  float scl[3], mn[3], bt[3];
#pragma unroll
  for (int ni = 0; ni < 3; ni++) {
    int ch = o0 + wc * 48 + ni * 16 + lr;
    scl[ni] = bns[ch * 4]; mn[ni] = bns[ch * 4 + 1]; bt[ni] = bns[ch * 4 + 2];
  }

  // staging: per 4KB round, row = r*32 + (tid>>3), dest chunk = tid&7,
  // source chunk pre-swizzled so LDS[row][chunk] = G[row][chunk ^ (row&7)]
  int srow = tid >> 3;
  u32 sgoff = (u32)(((tid & 7) ^ (srow & 7)) << 4);
  u32 ldst = (u32)tid * 16;

  u32 aoff[4], boff[3];
#pragma unroll
  for (int mi = 0; mi < 4; mi++) {
    int r = wr * 64 + mi * 16 + lr;
    aoff[mi] = r * 128 + ((lq ^ (r & 7)) << 4);
  }
#pragma unroll
  for (int ni = 0; ni < 3; ni++) {
    int r = wc * 48 + ni * 16 + lr;
    boff[ni] = r * 128 + ((lq ^ (r & 7)) << 4);
  }

  float vst[4][3][4];
#pragma unroll
  for (int a = 0; a < 4; a++)
#pragma unroll
    for (int b = 0; b < 3; b++)
#pragma unroll
      for (int c = 0; c < 4; c++) vst[a][b][c] = 0.f;

  const char* Bb = (const char*)wcat + (size_t)o0 * 2048;

  for (int t = 0; t < 4; t++) {
    f4 acc[4][3];
#pragma unroll
    for (int a = 0; a < 4; a++)
#pragma unroll
      for (int b = 0; b < 3; b++) { acc[a][b][0] = 0.f; acc[a][b][1] = 0.f; acc[a][b][2] = 0.f; acc[a][b][3] = 0.f; }

    const char* Ab = (const char*)xs + ((size_t)t * M2_ + m0) * 1024;
    for (int ks = 0; ks < 8; ks++) {
      u32 kb = (u32)ks * 128;
#pragma unroll
      for (int r = 0; r < 4; r++)
        gl_lds16(Ab + (size_t)(r * 32 + srow) * 1024 + kb + sgoff, (char*)lA + r * 4096 + ldst);
#pragma unroll
      for (int r = 0; r < 3; r++) {
        gl_lds16(Bb + (size_t)(r * 32 + srow) * 2048 + kb + sgoff, (char*)lBh + r * 4096 + ldst);
        gl_lds16(Bb + (size_t)(r * 32 + srow) * 2048 + 1024 + kb + sgoff, (char*)lBl + r * 4096 + ldst);
      }
      __syncthreads();
#pragma unroll
      for (int h = 0; h < 2; h++) {
        u32 hx = (u32)h << 6;       // flips chunk bit2 (+4 chunks) under XOR
        bh8 af[4], bf[3], lf[3];
#pragma unroll
        for (int mi = 0; mi < 4; mi++)
          af[mi] = *(const bh8*)((const char*)lA + (aoff[mi] ^ hx));
#pragma unroll
        for (int ni = 0; ni < 3; ni++) {
          bf[ni] = *(const bh8*)((const char*)lBh + (boff[ni] ^ hx));
          lf[ni] = *(const bh8*)((const char*)lBl + (boff[ni] ^ hx));
        }
#pragma unroll
        for (int mi = 0; mi < 4; mi++)
#pragma unroll
          for (int ni = 0; ni < 3; ni++)
            acc[mi][ni] = __builtin_amdgcn_mfma_f32_16x16x32_bf16(af[mi], bf[ni], acc[mi][ni], 0, 0, 0);
#pragma unroll
        for (int mi = 0; mi < 4; mi++)
#pragma unroll
          for (int ni = 0; ni < 3; ni++)
            acc[mi][ni] = __builtin_amdgcn_mfma_f32_16x16x32_bf16(af[mi], lf[ni], acc[mi][ni], 0, 0, 0);
      }
      __syncthreads();
    }
    // BN + LIF epilogue (v-state persists across t)
#pragma unroll
    for (int mi = 0; mi < 4; mi++)
#pragma unroll
      for (int ni = 0; ni < 3; ni++)
#pragma unroll
        for (int j = 0; j < 4; j++) {
          float y = acc[mi][ni][j];
          y = (y - mn[ni]) * scl[ni] + bt[ni];
          float vv = vst[mi][ni][j];
          vv = vv + (y - vv) * 0.5f;
          u16 s = 0;
          if (vv >= 1.0f) { s = 0x3F80; vv = 0.f; }
          vst[mi][ni][j] = vv;
          int r = m0 + wr * 64 + mi * 16 + lq * 4 + j;
          int o = o0 + wc * 48 + ni * 16 + lr;
          spq[((size_t)t * M2_ + r) * OC3_ + o] = s;
        }
  }
}

// ---------------- K3: fused kv-count partials + v-spike output ----------------
// grid 512 = (tb 64) x (n-chunk 8); partial counts to KVP (no atomics)
__global__ void k_kvv(const u16* __restrict__ spq, float* __restrict__ vout,
                      int* __restrict__ kvp) {
  int tb = blockIdx.x >> 3, nc = blockIdx.x & 7;
  int tid = threadIdx.x;
  const char* base = (const char*)spq + ((size_t)tb * 256 + nc * 32) * 3072;
  int c = tid * 2, h = c >> 6, d = c & 63;
  float* vo = vout + (((size_t)tb * 8 + h) * 256 + nc * 32) * 64 + d;
  int cnt0 = 0, cnt1 = 0;
  for (int n = 0; n < 32; n++) {
    u32 kk = *(const u32*)(base + (size_t)n * 3072 + 1024 + c * 2);
    u32 vv = *(const u32*)(base + (size_t)n * 3072 + 2048 + c * 2);
    u32 a = kk & vv;
    cnt0 += (a & 0xFFFFu) ? 1 : 0;
    cnt1 += (a >> 16) ? 1 : 0;
    float2 w;
    w.x = (vv & 0xFFFFu) ? 1.f : 0.f;
    w.y = (vv >> 16) ? 1.f : 0.f;
    *(float2*)(vo + (size_t)n * 64) = w;
  }
  kvp[((tb * 8 + nc) << 9) + c]     = cnt0;
  kvp[((tb * 8 + nc) << 9) + c + 1] = cnt1;
}

// ---------------- K4: talking-heads LIF (thresh 0.5) -> mask ----------------
__global__ void k_tlif(const int* __restrict__ kvp, unsigned char* __restrict__ mask) {
  int id = blockIdx.x * 256 + threadIdx.x;   // B_*C_ = 8192
  int b = id >> 9, c = id & 511;
  float v = 0.f;
  for (int t = 0; t < 4; t++) {
    int tb = t * 16 + b;
    int s = 0;
#pragma unroll
    for (int nc = 0; nc < 8; nc++) s += kvp[((tb * 8 + nc) << 9) + c];
    float xx = (float)s;
    v = v + (xx - v) * 0.5f;
    unsigned char sp = 0;
    if (v >= 0.5f) { sp = 1; v = 0.f; }
    mask[tb * 512 + c] = sp;
  }
}

// ---------------- K5: proj GEMM with in-reg mask-AND + fused BN/bias/identity ----------------
// A = q-spikes (cols 0..511 of SPQ rows) & mask[tb,c];  out[tb][o][n] = BN(y+bp) + x
__launch_bounds__(256, 2)
__global__ void k_proj_gemm(const u16* __restrict__ spq, const unsigned char* __restrict__ mask,
                            const u16* __restrict__ wpc, const float* __restrict__ pss,
                            const float* __restrict__ x, float* __restrict__ out) {
  __shared__ u16 lA[128 * 64];
  __shared__ u16 lBh[128 * 64];
  __shared__ u16 lBl[128 * 64];
  __shared__ u16 lm[512];
  int tid = threadIdx.x, lane = tid & 63, wid = tid >> 6;
  int wr = wid >> 1, wc = wid & 1, lr = lane & 15, lq = lane >> 4;
  int m0 = blockIdx.x * 128, o0 = blockIdx.y * 128;
  int tb = m0 >> 8;

  lm[tid]       = mask[tb * 512 + tid]       ? (u16)0xFFFF : (u16)0;
  lm[tid + 256] = mask[tb * 512 + tid + 256] ? (u16)0xFFFF : (u16)0;

  int srow = tid >> 3;
  u32 sgoff = (u32)(((tid & 7) ^ (srow & 7)) << 4);
  u32 ldst = (u32)tid * 16;

  u32 aoff[4], boff[4];
#pragma unroll
  for (int mi = 0; mi < 4; mi++) {
    int r = wr * 64 + mi * 16 + lr;
    aoff[mi] = r * 128 + ((lq ^ (r & 7)) << 4);
  }
#pragma unroll
  for (int ni = 0; ni < 4; ni++) {
    int r = wc * 64 + ni * 16 + lr;
    boff[ni] = r * 128 + ((lq ^ (r & 7)) << 4);
  }

  f4 acc[4][4];
#pragma unroll
  for (int a = 0; a < 4; a++)
#pragma unroll
    for (int b = 0; b < 4; b++) { acc[a][b][0] = 0.f; acc[a][b][1] = 0.f; acc[a][b][2] = 0.f; acc[a][b][3] = 0.f; }

  const char* Ab = (const char*)spq + (size_t)m0 * 3072;
  const char* Bb = (const char*)wpc + (size_t)o0 * 2048;

  for (int ks = 0; ks < 8; ks++) {
    u32 kb = (u32)ks * 128;
#pragma unroll
    for (int r = 0; r < 4; r++) {
      gl_lds16(Ab + (size_t)(r * 32 + srow) * 3072 + kb + sgoff, (char*)lA + r * 4096 + ldst);
      gl_lds16(Bb + (size_t)(r * 32 + srow) * 2048 + kb + sgoff, (char*)lBh + r * 4096 + ldst);
      gl_lds16(Bb + (size_t)(r * 32 + srow) * 2048 + 1024 + kb + sgoff, (char*)lBl + r * 4096 + ldst);
    }
    __syncthreads();
#pragma unroll
    for (int h = 0; h < 2; h++) {
      u32 hx = (u32)h << 6;
      bh8 mq = *(const bh8*)((const char*)lm + kb + (h << 6) + lq * 16);  // broadcast per lq
      bh8 af[4], bf[4], lf[4];
#pragma unroll
      for (int mi = 0; mi < 4; mi++) {
        af[mi] = *(const bh8*)((const char*)lA + (aoff[mi] ^ hx));
        af[mi] = af[mi] & mq;      // q-spike AND kv-mask (0x3F80 & 0xFFFF)
      }
#pragma unroll
      for (int ni = 0; ni < 4; ni++) {
        bf[ni] = *(const bh8*)((const char*)lBh + (boff[ni] ^ hx));
        lf[ni] = *(const bh8*)((const char*)lBl + (boff[ni] ^ hx));
      }
#pragma unroll
      for (int mi = 0; mi < 4; mi++)
#pragma unroll
        for (int ni = 0; ni < 4; ni++)
          acc[mi][ni] = __builtin_amdgcn_mfma_f32_16x16x32_bf16(af[mi], bf[ni], acc[mi][ni], 0, 0, 0);
#pragma unroll
      for (int mi = 0; mi < 4; mi++)
#pragma unroll
        for (int ni = 0; ni < 4; ni++)
          acc[mi][ni] = __builtin_amdgcn_mfma_f32_16x16x32_bf16(af[mi], lf[ni], acc[mi][ni], 0, 0, 0);
    }
    __syncthreads();
  }
  // fused epilogue: BN(y + bp) + identity, transposed store to out[tb][o][n]
#pragma unroll
  for (int mi = 0; mi < 4; mi++)
#pragma unroll
    for (int ni = 0; ni < 4; ni++) {
      int o = o0 + wc * 64 + ni * 16 + lr;
      f4 ps = *(const f4*)&pss[o * 4];        // {bp, pm, scale, beta}
      int n = (m0 & 255) + wr * 64 + mi * 16 + lq * 4;
      size_t idx = (size_t)tb * 131072 + (size_t)o * 256 + n;
      f4 xv = *(const f4*)&x[idx];
      f4 res;
#pragma unroll
      for (int j = 0; j < 4; j++) {
        float u = acc[mi][ni][j] + ps[0];
        u = (u - ps[1]) * ps[2] + ps[3];
        res[j] = u + xv[j];
      }
      *(f4*)&out[idx] = res;
    }
}

// ---------------- launch ----------------
extern "C" void kernel_launch(void* const* d_in, const int* in_sizes, int n_in,
                              void* d_out, int out_size, void* d_ws, size_t ws_size,
                              hipStream_t stream) {
  const float* x  = (const float*)d_in[0];
  const float* wq = (const float*)d_in[1];
  const float* qg = (const float*)d_in[2];
  const float* qb = (const float*)d_in[3];
  const float* qm = (const float*)d_in[4];
  const float* qv = (const float*)d_in[5];
  const float* wk = (const float*)d_in[6];
  const float* kg = (const float*)d_in[7];
  const float* kb = (const float*)d_in[8];
  const float* km = (const float*)d_in[9];
  const float* kv = (const float*)d_in[10];
  const float* wv = (const float*)d_in[11];
  const float* vg = (const float*)d_in[12];
  const float* vb = (const float*)d_in[13];
  const float* vm = (const float*)d_in[14];
  const float* vv = (const float*)d_in[15];
  const float* wp = (const float*)d_in[16];
  const float* bp = (const float*)d_in[17];
  const float* pg = (const float*)d_in[18];
  const float* pb = (const float*)d_in[19];
  const float* pm = (const float*)d_in[20];
  const float* pv = (const float*)d_in[21];

  char* w = (char*)d_ws;
  u16*  XS    = (u16*)(w + 0);                    // 16 MiB (T,B,N,C) bf16
  u16*  SPQ   = (u16*)(w + 16777216);             // 48 MiB (T*M2, 1536) bf16
  u16*  WCAT  = (u16*)(w + 67108864);             // 3 MiB
  u16*  WPCAT = (u16*)(w + 70254592);             // 1 MiB
  float* BNS  = (float*)(w + 71303168);           // 24 KiB
  float* PSS  = (float*)(w + 71327744);           // 8 KiB
  int*   KVP  = (int*)(w + 71335936);             // 1 MiB  (64*8, 512) int partials
  unsigned char* MASK = (unsigned char*)(w + 72384512); // 32 KiB

  float* out  = (float*)d_out;                    // (T,B,C,N) f32
  float* vout = out + 8388608;                    // (T,B,8,N,64) f32

  k_prep_w<<<4096, 256, 0, stream>>>(wq, wk, wv, wp, WCAT, WPCAT);
  k_prep_c<<<8, 256, 0, stream>>>(qg, qb, qm, qv, kg, kb, km, kv,
                                  vg, vb, vm, vv, pg, pb, pm, pv, bp, BNS, PSS);
  k_lif_x<<<dim3(4, 8, 16), 256, 0, stream>>>(x, XS);
  k_qkv_gemm<<<dim3(32, 16), 256, 0, stream>>>(XS, WCAT, BNS, SPQ);
  k_kvv<<<512, 256, 0, stream>>>(SPQ, vout, KVP);
  k_tlif<<<32, 256, 0, stream>>>(KVP, MASK);
  k_proj_gemm<<<dim3(128, 4), 256, 0, stream>>>(SPQ, MASK, WPCAT, PSS, x, out);
}